// Round 1
// baseline (1462.514 us; speedup 1.0000x reference)
//
#include <hip/hip_runtime.h>
#include <hip/hip_bf16.h>
#include <stdint.h>

typedef __bf16 bf16_t;
typedef __bf16 bf16x8 __attribute__((ext_vector_type(8)));
typedef float f32x4 __attribute__((ext_vector_type(4)));

#define HID 128

// --- swizzled LDS addressing: byte ^= ((row&7)<<4), applied within a row ---
__device__ __forceinline__ bf16_t* swz(bf16_t* base, int row, int rowBytes, int byteInRow) {
    return (bf16_t*)((char*)base + row * rowBytes + (byteInRow ^ ((row & 7) << 4)));
}
__device__ __forceinline__ const bf16_t* swzc(const bf16_t* base, int row, int rowBytes, int byteInRow) {
    return (const bf16_t*)((const char*)base + row * rowBytes + (byteInRow ^ ((row & 7) << 4)));
}

__device__ __forceinline__ bf16x8 pack8(float4 a, float4 b) {
    bf16x8 r;
    r[0] = (bf16_t)a.x; r[1] = (bf16_t)a.y; r[2] = (bf16_t)a.z; r[3] = (bf16_t)a.w;
    r[4] = (bf16_t)b.x; r[5] = (bf16_t)b.y; r[6] = (bf16_t)b.z; r[7] = (bf16_t)b.w;
    return r;
}

// edge_index may be int32 (JAX default) or int64. If int64 (values < 2^31),
// every odd int32 word is 0. Detect once; false-positive prob ~0.
__device__ __forceinline__ bool is_i64(const int* ei) {
    return ((ei[1] | ei[3] | ei[5] | ei[7]) == 0);
}
__device__ __forceinline__ int eidx(const int* __restrict__ ei, int i, bool i64) {
    return i64 ? ei[2 * i] : ei[i];
}

// =====================  PREP: transpose + bf16-convert weights  =====================
// layout in ws (bytes):
//   w1t   @0       : [128][256] bf16  (W1^T, k<256 rows of we1)     65536
//   w1last@65536   : [128] f32        (we1 row 256, radial weights)   512
//   w2t   @66048   : [128][128] bf16                                32768
//   wc1t  @98816   : [128][128] bf16                                32768
//   wn1t  @131584  : [128][256] bf16  (k<128: wn1a+wn1b, k>=128: wn1c) 65536
//   wn2t  @197120  : [128][128] bf16                                32768
//   wv1t  @229888  : [128][128] bf16                                32768
//   num   @262656  : [N][3] f32
//   cnt   @262656+N*12 : [N] f32
__global__ void prep_kernel(const float* __restrict__ we1, const float* __restrict__ we2,
                            const float* __restrict__ wc1, const float* __restrict__ wn1,
                            const float* __restrict__ wn2, const float* __restrict__ wv1,
                            bf16_t* w1t, float* w1last, bf16_t* w2t, bf16_t* wc1t,
                            bf16_t* wn1t, bf16_t* wn2t, bf16_t* wv1t) {
    int idx = blockIdx.x * 256 + threadIdx.x;
    if (idx < 32768) { int j = idx >> 8, k = idx & 255; w1t[idx] = (bf16_t)we1[k * 128 + j]; return; }
    idx -= 32768;
    if (idx < 128) { w1last[idx] = we1[256 * 128 + idx]; return; }
    idx -= 128;
    if (idx < 16384) { int j = idx >> 7, k = idx & 127; w2t[idx] = (bf16_t)we2[k * 128 + j]; return; }
    idx -= 16384;
    if (idx < 16384) { int j = idx >> 7, k = idx & 127; wc1t[idx] = (bf16_t)wc1[k * 128 + j]; return; }
    idx -= 16384;
    if (idx < 32768) {
        int j = idx >> 8, k = idx & 255;
        float val = (k < 128) ? (wn1[k * 128 + j] + wn1[(k + 128) * 128 + j])
                              : wn1[(k + 128) * 128 + j];
        wn1t[idx] = (bf16_t)val; return;
    }
    idx -= 32768;
    if (idx < 16384) { int j = idx >> 7, k = idx & 127; wn2t[idx] = (bf16_t)wn2[k * 128 + j]; return; }
    idx -= 16384;
    if (idx < 16384) { int j = idx >> 7, k = idx & 127; wv1t[idx] = (bf16_t)wv1[k * 128 + j]; return; }
}

// =====================  EDGE KERNEL  =====================
// 8 waves/block, each wave owns 16 edges per tile, grid-strided. No in-loop barriers.
// LDS: W1t (64K, swz rows of 512B) + W2t (32K, swz rows of 256B) + 8 waves * 2 * 4KB bufs = 160KiB exact.
__global__ __launch_bounds__(512, 2) void edge_kernel(
    const float* __restrict__ h, const int* __restrict__ ei, const float* __restrict__ x,
    const float* __restrict__ be1, const float* __restrict__ be2,
    const float* __restrict__ bc1, const float* __restrict__ wc2,
    const bf16_t* __restrict__ w1t, const float* __restrict__ w1last,
    const bf16_t* __restrict__ w2t, const bf16_t* __restrict__ wc1t,
    float* __restrict__ agg, float* __restrict__ num, float* __restrict__ cnt,
    int M, int N) {
    __shared__ bf16_t lw1[128 * 256];
    __shared__ bf16_t lw2[128 * 128];
    __shared__ bf16_t lbuf[8][2][16 * 128];

    const int tid = threadIdx.x;
    for (int c = tid; c < 4096; c += 512) {
        int row = c >> 5, cin = c & 31;
        float4 d4 = ((const float4*)w1t)[c];
        *(float4*)swz(lw1, row, 512, cin * 16) = d4;
    }
    for (int c = tid; c < 2048; c += 512) {
        int row = c >> 4, cin = c & 15;
        float4 d4 = ((const float4*)w2t)[c];
        *(float4*)swz(lw2, row, 256, cin * 16) = d4;
    }
    __syncthreads();

    const bool i64 = is_i64(ei);
    const int wave = tid >> 6, lane = tid & 63;
    const int l15 = lane & 15, l4 = lane >> 4;
    bf16_t* b0 = lbuf[wave][0];
    bf16_t* b1 = lbuf[wave][1];
    const int wid = blockIdx.x * 8 + wave;
    const int stride = gridDim.x * 8;
    const int ntiles = M >> 4;

    for (int t = wid; t < ntiles; t += stride) {
        const int e0 = t << 4;
        const int s = lane >> 2, p = lane & 3;
        const int er = eidx(ei, e0 + s, i64);
        const int ec = eidx(ei, M + e0 + s, i64);
        const float* hr = h + (size_t)er * HID + p * 32;
        const float* hc = h + (size_t)ec * HID + p * 32;
#pragma unroll
        for (int c2 = 0; c2 < 4; c2++) {
            float4 a = *(const float4*)(hr + c2 * 8);
            float4 b = *(const float4*)(hr + c2 * 8 + 4);
            *(bf16x8*)swz(b0, s, 256, (p * 4 + c2) * 16) = pack8(a, b);
        }
#pragma unroll
        for (int c2 = 0; c2 < 4; c2++) {
            float4 a = *(const float4*)(hc + c2 * 8);
            float4 b = *(const float4*)(hc + c2 * 8 + 4);
            *(bf16x8*)swz(b1, s, 256, (p * 4 + c2) * 16) = pack8(a, b);
        }
        float d0 = x[er * 3 + 0] - x[ec * 3 + 0];
        float d1 = x[er * 3 + 1] - x[ec * 3 + 1];
        float d2 = x[er * 3 + 2] - x[ec * 3 + 2];
        float radial = d0 * d0 + d1 * d1 + d2 * d2;
        __builtin_amdgcn_wave_barrier();

        // per-output-row copies of radial/diff (computed by lane 4*r of each 16-group)
        float rad4[4], dx4[4], dy4[4], dz4[4];
#pragma unroll
        for (int r = 0; r < 4; r++) {
            int src = (l4 * 4 + r) * 4;
            rad4[r] = __shfl(radial, src, 64);
            dx4[r] = __shfl(d0, src, 64);
            dy4[r] = __shfl(d1, src, 64);
            dz4[r] = __shfl(d2, src, 64);
        }

        // ---- layer 1: [16,256]@[256,128] + radial rank-1 + bias ----
        f32x4 acc[8];
#pragma unroll
        for (int n = 0; n < 8; n++) {
            int j = n * 16 + l15;
            float bb = be1[j], wl = w1last[j];
#pragma unroll
            for (int r = 0; r < 4; r++) acc[n][r] = bb + rad4[r] * wl;
        }
#pragma unroll
        for (int kk = 0; kk < 8; kk++) {
            const bf16_t* ab = (kk < 4) ? b0 : b1;
            bf16x8 af = *(const bf16x8*)swzc(ab, l15, 256, (kk & 3) * 64 + l4 * 16);
#pragma unroll
            for (int n = 0; n < 8; n++) {
                bf16x8 bf = *(const bf16x8*)swzc(lw1, n * 16 + l15, 512, kk * 64 + l4 * 16);
                acc[n] = __builtin_amdgcn_mfma_f32_16x16x32_bf16(af, bf, acc[n], 0, 0, 0);
            }
        }
#pragma unroll
        for (int n = 0; n < 8; n++) {
#pragma unroll
            for (int r = 0; r < 4; r++) {
                int rw = l4 * 4 + r;
                *swz(b0, rw, 256, (n * 16 + l15) * 2) = (bf16_t)fmaxf(acc[n][r], 0.f);
            }
        }
        __builtin_amdgcn_wave_barrier();

        // ---- layer 2: [16,128]@[128,128] ----
        f32x4 acc2[8];
#pragma unroll
        for (int n = 0; n < 8; n++) {
            float bb = be2[n * 16 + l15];
#pragma unroll
            for (int r = 0; r < 4; r++) acc2[n][r] = bb;
        }
#pragma unroll
        for (int kk = 0; kk < 4; kk++) {
            bf16x8 af = *(const bf16x8*)swzc(b0, l15, 256, kk * 64 + l4 * 16);
#pragma unroll
            for (int n = 0; n < 8; n++) {
                bf16x8 bf = *(const bf16x8*)swzc(lw2, n * 16 + l15, 256, kk * 64 + l4 * 16);
                acc2[n] = __builtin_amdgcn_mfma_f32_16x16x32_bf16(af, bf, acc2[n], 0, 0, 0);
            }
        }
        float ef[8][4];
#pragma unroll
        for (int n = 0; n < 8; n++) {
#pragma unroll
            for (int r = 0; r < 4; r++) {
                float v_ = fmaxf(acc2[n][r], 0.f);
                ef[n][r] = v_;
                int rw = l4 * 4 + r;
                *swz(b1, rw, 256, (n * 16 + l15) * 2) = (bf16_t)v_;
            }
        }
        __builtin_amdgcn_wave_barrier();

        // ---- gate: relu([16,128]@Wc1+bc1)@wc2, Wc1t streamed from global (L1-resident) ----
        f32x4 acc3[8];
#pragma unroll
        for (int n = 0; n < 8; n++) {
            float bb = bc1[n * 16 + l15];
#pragma unroll
            for (int r = 0; r < 4; r++) acc3[n][r] = bb;
        }
#pragma unroll
        for (int kk = 0; kk < 4; kk++) {
            bf16x8 af = *(const bf16x8*)swzc(b1, l15, 256, kk * 64 + l4 * 16);
#pragma unroll
            for (int n = 0; n < 8; n++) {
                bf16x8 bf = *(const bf16x8*)(wc1t + (n * 16 + l15) * 128 + kk * 32 + l4 * 8);
                acc3[n] = __builtin_amdgcn_mfma_f32_16x16x32_bf16(af, bf, acc3[n], 0, 0, 0);
            }
        }
        float pr[4] = {0.f, 0.f, 0.f, 0.f};
#pragma unroll
        for (int n = 0; n < 8; n++) {
            float w = wc2[n * 16 + l15];
#pragma unroll
            for (int r = 0; r < 4; r++) pr[r] += fmaxf(acc3[n][r], 0.f) * w;
        }
#pragma unroll
        for (int m = 1; m < 16; m <<= 1) {
#pragma unroll
            for (int r = 0; r < 4; r++) pr[r] += __shfl_xor(pr[r], m, 16);
        }

        // ---- num / cnt atomics (one lane per 16-group handles its 4 edges) ----
        if (l15 == 0) {
#pragma unroll
            for (int r = 0; r < 4; r++) {
                int e = e0 + l4 * 4 + r;
                int re = eidx(ei, e, i64);
                float g = pr[r];
                float t0 = fminf(fmaxf(dx4[r] * g, -100.f), 100.f);
                float t1 = fminf(fmaxf(dy4[r] * g, -100.f), 100.f);
                float t2 = fminf(fmaxf(dz4[r] * g, -100.f), 100.f);
                atomicAdd(num + (size_t)re * 3 + 0, t0);
                atomicAdd(num + (size_t)re * 3 + 1, t1);
                atomicAdd(num + (size_t)re * 3 + 2, t2);
                atomicAdd(cnt + re, 1.0f);
            }
        }
        // ---- agg atomics: edge_feat (f32 from regs) into agg[row] ----
#pragma unroll
        for (int r = 0; r < 4; r++) {
            int e = e0 + l4 * 4 + r;
            int re = eidx(ei, e, i64);
            float* basep = agg + (size_t)re * HID + l15;
#pragma unroll
            for (int n = 0; n < 8; n++) atomicAdd(basep + n * 16, ef[n][r]);
        }
    }
}

// =====================  NODE KERNEL  =====================
// 4 waves/block, 16 nodes/wave-tile. agg lives in out_h (overwritten with h_new).
__global__ __launch_bounds__(256, 1) void node_kernel(
    const float* __restrict__ h, const float* __restrict__ x, const float* __restrict__ v,
    const float* __restrict__ bn1, const float* __restrict__ bn2,
    const float* __restrict__ bv1, const float* __restrict__ bv2,
    const float* __restrict__ wv2,
    const bf16_t* __restrict__ wn1t, const bf16_t* __restrict__ wn2t,
    const bf16_t* __restrict__ wv1t,
    const float* __restrict__ num, const float* __restrict__ cnt,
    float* __restrict__ out_h, float* __restrict__ out_x, float* __restrict__ out_v,
    int N) {
    __shared__ bf16_t lw1[128 * 256];
    __shared__ bf16_t lw2[128 * 128];
    __shared__ bf16_t lbuf[4][3][16 * 128];

    const int tid = threadIdx.x;
    for (int c = tid; c < 4096; c += 256) {
        int row = c >> 5, cin = c & 31;
        *(float4*)swz(lw1, row, 512, cin * 16) = ((const float4*)wn1t)[c];
    }
    for (int c = tid; c < 2048; c += 256) {
        int row = c >> 4, cin = c & 15;
        *(float4*)swz(lw2, row, 256, cin * 16) = ((const float4*)wn2t)[c];
    }
    __syncthreads();

    const int wave = tid >> 6, lane = tid & 63;
    const int l15 = lane & 15, l4 = lane >> 4;
    bf16_t* b0 = lbuf[wave][0];
    bf16_t* b1 = lbuf[wave][1];
    bf16_t* b2 = lbuf[wave][2];
    const int wid = blockIdx.x * 4 + wave;
    const int stride = gridDim.x * 4;
    const int nt = N >> 4;

    for (int t = wid; t < nt; t += stride) {
        const int m0 = t << 4;
        const int s = lane >> 2, p = lane & 3;
        const float* hp = h + (size_t)(m0 + s) * HID + p * 32;
        const float* ap = out_h + (size_t)(m0 + s) * HID + p * 32;  // agg
#pragma unroll
        for (int c2 = 0; c2 < 4; c2++) {
            float4 a = *(const float4*)(hp + c2 * 8);
            float4 b = *(const float4*)(hp + c2 * 8 + 4);
            *(bf16x8*)swz(b0, s, 256, (p * 4 + c2) * 16) = pack8(a, b);
        }
#pragma unroll
        for (int c2 = 0; c2 < 4; c2++) {
            float fa[8];
            *(float4*)fa = *(const float4*)(ap + c2 * 8);
            *(float4*)(fa + 4) = *(const float4*)(ap + c2 * 8 + 4);
            bf16x8 hi8, lo8;
#pragma unroll
            for (int i = 0; i < 8; i++) {
                bf16_t hi = (bf16_t)fa[i];
                hi8[i] = hi;
                lo8[i] = (bf16_t)(fa[i] - (float)hi);  // agg = hi + lo (bf16 pair, ~f32 accurate)
            }
            *(bf16x8*)swz(b1, s, 256, (p * 4 + c2) * 16) = hi8;
            *(bf16x8*)swz(b2, s, 256, (p * 4 + c2) * 16) = lo8;
        }
        __builtin_amdgcn_wave_barrier();

        // ---- vel gate: relu(h@wv1+bv1)@wv2 + bv2 ----
        f32x4 av[8];
#pragma unroll
        for (int n = 0; n < 8; n++) {
            float bb = bv1[n * 16 + l15];
#pragma unroll
            for (int r = 0; r < 4; r++) av[n][r] = bb;
        }
#pragma unroll
        for (int kk = 0; kk < 4; kk++) {
            bf16x8 af = *(const bf16x8*)swzc(b0, l15, 256, kk * 64 + l4 * 16);
#pragma unroll
            for (int n = 0; n < 8; n++) {
                bf16x8 bf = *(const bf16x8*)(wv1t + (n * 16 + l15) * 128 + kk * 32 + l4 * 8);
                av[n] = __builtin_amdgcn_mfma_f32_16x16x32_bf16(af, bf, av[n], 0, 0, 0);
            }
        }
        float pv[4] = {0.f, 0.f, 0.f, 0.f};
#pragma unroll
        for (int n = 0; n < 8; n++) {
            float w = wv2[n * 16 + l15];
#pragma unroll
            for (int r = 0; r < 4; r++) pv[r] += fmaxf(av[n][r], 0.f) * w;
        }
#pragma unroll
        for (int m = 1; m < 16; m <<= 1) {
#pragma unroll
            for (int r = 0; r < 4; r++) pv[r] += __shfl_xor(pv[r], m, 16);
        }
        float bv2v = bv2[0];
        if (l15 == 0) {
#pragma unroll
            for (int r = 0; r < 4; r++) {
                int m = m0 + l4 * 4 + r;
                float vg = pv[r] + bv2v;
                float c = cnt[m];
                float inv = 1.0f / fmaxf(c, 1.0f);
#pragma unroll
                for (int i = 0; i < 3; i++) {
                    float f = num[(size_t)m * 3 + i] * inv;
                    float vn = vg * v[(size_t)m * 3 + i] + f;
                    out_v[(size_t)m * 3 + i] = vn;
                    out_x[(size_t)m * 3 + i] = x[(size_t)m * 3 + i] + vn;
                }
            }
        }

        // ---- node MLP layer1: K = 128(h via wn1a+wn1b) + 128(agg hi) + 128(agg lo) ----
        f32x4 a1[8];
#pragma unroll
        for (int n = 0; n < 8; n++) {
            float bb = bn1[n * 16 + l15];
#pragma unroll
            for (int r = 0; r < 4; r++) a1[n][r] = bb;
        }
#pragma unroll
        for (int kk = 0; kk < 12; kk++) {
            const bf16_t* ab = (kk < 4) ? b0 : ((kk < 8) ? b1 : b2);
            bf16x8 af = *(const bf16x8*)swzc(ab, l15, 256, (kk & 3) * 64 + l4 * 16);
            int kb = (kk < 8) ? kk : (kk - 4);
#pragma unroll
            for (int n = 0; n < 8; n++) {
                bf16x8 bf = *(const bf16x8*)swzc(lw1, n * 16 + l15, 512, kb * 64 + l4 * 16);
                a1[n] = __builtin_amdgcn_mfma_f32_16x16x32_bf16(af, bf, a1[n], 0, 0, 0);
            }
        }
#pragma unroll
        for (int n = 0; n < 8; n++) {
#pragma unroll
            for (int r = 0; r < 4; r++) {
                int rw = l4 * 4 + r;
                *swz(b0, rw, 256, (n * 16 + l15) * 2) = (bf16_t)fmaxf(a1[n][r], 0.f);
            }
        }
        __builtin_amdgcn_wave_barrier();

        // ---- layer2 + residual ----
        f32x4 a2[8];
#pragma unroll
        for (int n = 0; n < 8; n++) {
            float bb = bn2[n * 16 + l15];
#pragma unroll
            for (int r = 0; r < 4; r++) a2[n][r] = bb;
        }
#pragma unroll
        for (int kk = 0; kk < 4; kk++) {
            bf16x8 af = *(const bf16x8*)swzc(b0, l15, 256, kk * 64 + l4 * 16);
#pragma unroll
            for (int n = 0; n < 8; n++) {
                bf16x8 bf = *(const bf16x8*)swzc(lw2, n * 16 + l15, 256, kk * 64 + l4 * 16);
                a2[n] = __builtin_amdgcn_mfma_f32_16x16x32_bf16(af, bf, a2[n], 0, 0, 0);
            }
        }
#pragma unroll
        for (int n = 0; n < 8; n++) {
            int j = n * 16 + l15;
#pragma unroll
            for (int r = 0; r < 4; r++) {
                int m = m0 + l4 * 4 + r;
                out_h[(size_t)m * HID + j] = h[(size_t)m * HID + j] + a2[n][r];
            }
        }
    }
}

extern "C" void kernel_launch(void* const* d_in, const int* in_sizes, int n_in,
                              void* d_out, int out_size, void* d_ws, size_t ws_size,
                              hipStream_t stream) {
    const float* h   = (const float*)d_in[0];
    const int*   ei  = (const int*)d_in[1];
    const float* x   = (const float*)d_in[2];
    const float* v   = (const float*)d_in[3];
    const float* we1 = (const float*)d_in[4];
    const float* be1 = (const float*)d_in[5];
    const float* we2 = (const float*)d_in[6];
    const float* be2 = (const float*)d_in[7];
    const float* wn1 = (const float*)d_in[8];
    const float* bn1 = (const float*)d_in[9];
    const float* wn2 = (const float*)d_in[10];
    const float* bn2 = (const float*)d_in[11];
    const float* wv1 = (const float*)d_in[12];
    const float* bv1 = (const float*)d_in[13];
    const float* wv2 = (const float*)d_in[14];
    const float* bv2 = (const float*)d_in[15];
    const float* wc1 = (const float*)d_in[16];
    const float* bc1 = (const float*)d_in[17];
    const float* wc2 = (const float*)d_in[18];

    const int N = in_sizes[0] / HID;
    const int M = in_sizes[1] / 2;

    float* out_h = (float*)d_out;
    float* out_x = out_h + (size_t)N * HID;
    float* out_v = out_x + (size_t)N * 3;

    char* ws = (char*)d_ws;
    bf16_t* w1t    = (bf16_t*)(ws + 0);
    float*  w1last = (float*)(ws + 65536);
    bf16_t* w2t    = (bf16_t*)(ws + 66048);
    bf16_t* wc1t   = (bf16_t*)(ws + 98816);
    bf16_t* wn1t   = (bf16_t*)(ws + 131584);
    bf16_t* wn2t   = (bf16_t*)(ws + 197120);
    bf16_t* wv1t   = (bf16_t*)(ws + 229888);
    float*  num    = (float*)(ws + 262656);
    float*  cnt    = (float*)(ws + 262656 + (size_t)N * 3 * 4);

    // zero agg (out_h region) + num + cnt
    hipMemsetAsync(out_h, 0, (size_t)N * HID * sizeof(float), stream);
    hipMemsetAsync(ws + 262656, 0, (size_t)N * 4 * 4, stream);

    prep_kernel<<<513, 256, 0, stream>>>(we1, we2, wc1, wn1, wn2, wv1,
                                         w1t, w1last, w2t, wc1t, wn1t, wn2t, wv1t);
    edge_kernel<<<256, 512, 0, stream>>>(h, ei, x, be1, be2, bc1, wc2,
                                         w1t, w1last, w2t, wc1t,
                                         out_h, num, cnt, M, N);
    node_kernel<<<256, 256, 0, stream>>>(h, x, v, bn1, bn2, bv1, bv2, wv2,
                                         wn1t, wn2t, wv1t, num, cnt,
                                         out_h, out_x, out_v, N);
}